// Round 1
// baseline (2119.412 us; speedup 1.0000x reference)
//
#include <hip/hip_runtime.h>
#include <math.h>

// Shapes (fixed by the problem)
#define DIMC  1024
#define NHEAD 16
#define HD    64
#define NB    4
#define NX    1024
#define NC    2048

// ---------------------------------------------------------------------------
// Tiled fp32 GEMM, 64x64 tile, 256 threads, 4x4 micro-tile, K-tile 16.
// MODE 0: C = A@B, then RoPE with pos -> out0 laid out (B, H, NX, HD)
// MODE 1: C = A@B (N=2048). cols<1024: K + RoPE -> out0 (B,H,NC,HD);
//         cols>=1024: V -> out1 (B,H,NC,HD)
// MODE 2: C = A@B + bias -> out0 row-major (M, N)
// ---------------------------------------------------------------------------
template <int MODE>
__global__ __launch_bounds__(256) void gemm_fused(
    const float* __restrict__ A, const float* __restrict__ B,
    const float* __restrict__ pos, const float* __restrict__ bias,
    float* __restrict__ out0, float* __restrict__ out1,
    int M, int N, int K)
{
    __shared__ float As[16][68];   // A^T tile: As[k][m], padded to avoid conflicts
    __shared__ float Bs[16][64];   // B tile: Bs[k][n]
    __shared__ float Ct[64][66];   // raw result staging for RoPE pairing

    const int tid = threadIdx.x;
    const int tx = tid & 15, ty = tid >> 4;
    const int m0 = blockIdx.y * 64, n0 = blockIdx.x * 64;

    float acc[4][4];
#pragma unroll
    for (int i = 0; i < 4; ++i)
#pragma unroll
        for (int j = 0; j < 4; ++j) acc[i][j] = 0.f;

    const int arow = tid >> 2;          // 0..63
    const int ak4  = (tid & 3) << 2;    // 0,4,8,12
    const int bk   = tid >> 4;          // 0..15
    const int bn4  = (tid & 15) << 2;   // 0..60

    const float* Aptr = A + (size_t)(m0 + arow) * K + ak4;
    const float* Bptr = B + (size_t)bk * N + n0 + bn4;

    for (int k0 = 0; k0 < K; k0 += 16) {
        float4 av = *(const float4*)(Aptr + k0);
        float4 bv = *(const float4*)(Bptr + (size_t)k0 * N);
        As[ak4 + 0][arow] = av.x;
        As[ak4 + 1][arow] = av.y;
        As[ak4 + 2][arow] = av.z;
        As[ak4 + 3][arow] = av.w;
        *(float4*)&Bs[bk][bn4] = bv;
        __syncthreads();
#pragma unroll
        for (int kk = 0; kk < 16; ++kk) {
            float4 a = *(const float4*)&As[kk][ty << 2];
            float4 b = *(const float4*)&Bs[kk][tx << 2];
            acc[0][0] += a.x * b.x; acc[0][1] += a.x * b.y; acc[0][2] += a.x * b.z; acc[0][3] += a.x * b.w;
            acc[1][0] += a.y * b.x; acc[1][1] += a.y * b.y; acc[1][2] += a.y * b.z; acc[1][3] += a.y * b.w;
            acc[2][0] += a.z * b.x; acc[2][1] += a.z * b.y; acc[2][2] += a.z * b.z; acc[2][3] += a.z * b.w;
            acc[3][0] += a.w * b.x; acc[3][1] += a.w * b.y; acc[3][2] += a.w * b.z; acc[3][3] += a.w * b.w;
        }
        __syncthreads();
    }

    if (MODE == 2) {
#pragma unroll
        for (int i = 0; i < 4; ++i) {
            const int m = m0 + (ty << 2) + i;
            float* op = out0 + (size_t)m * N + n0 + (tx << 2);
#pragma unroll
            for (int j = 0; j < 4; ++j)
                op[j] = acc[i][j] + bias[n0 + (tx << 2) + j];
        }
        return;
    }

    // stage raw tile so each thread can read its RoPE partner column (d ^ 32)
#pragma unroll
    for (int i = 0; i < 4; ++i)
#pragma unroll
        for (int j = 0; j < 4; ++j)
            Ct[(ty << 2) + i][(tx << 2) + j] = acc[i][j];
    __syncthreads();

    if (MODE == 0) {
        const int h = n0 >> 6;  // N==1024, 64-wide tiles align with heads
#pragma unroll
        for (int i = 0; i < 4; ++i) {
            const int m = m0 + (ty << 2) + i;
            const int b = m >> 10, n = m & 1023;  // NX = 1024
#pragma unroll
            for (int j = 0; j < 4; ++j) {
                const int d = (tx << 2) + j;
                const float th  = pos[n * HD + d];
                const float val = Ct[(ty << 2) + i][d];
                const float pv  = Ct[(ty << 2) + i][d ^ 32];
                const float o = val * cosf(th) + (d < 32 ? -pv : pv) * sinf(th);
                out0[(((size_t)(b * NHEAD + h)) * NX + n) * HD + d] = o;
            }
        }
    } else {  // MODE 1
        const int pair = n0 >> 10;           // 0 = K, 1 = V (block-uniform)
        const int h = (n0 & 1023) >> 6;
#pragma unroll
        for (int i = 0; i < 4; ++i) {
            const int m = m0 + (ty << 2) + i;
            const int b = m >> 11, n = m & 2047;  // NC = 2048
#pragma unroll
            for (int j = 0; j < 4; ++j) {
                const int d = (tx << 2) + j;
                const float val = Ct[(ty << 2) + i][d];
                if (pair == 0) {
                    const float th = pos[n * HD + d];
                    const float pv = Ct[(ty << 2) + i][d ^ 32];
                    const float o = val * cosf(th) + (d < 32 ? -pv : pv) * sinf(th);
                    out0[(((size_t)(b * NHEAD + h)) * NC + n) * HD + d] = o;
                } else {
                    out1[(((size_t)(b * NHEAD + h)) * NC + n) * HD + d] = val;
                }
            }
        }
    }
}

// ---------------------------------------------------------------------------
// Flash attention: one q-row per thread, 128 threads/block, K/V tiles of 32
// rows staged in LDS (all lanes read the same Ks/Vs element -> broadcast).
// Scores go through LDS Sl[kk][tid] (bank-stride 128 -> 2-way, free) to avoid
// runtime-indexed register arrays.
// ---------------------------------------------------------------------------
__global__ __launch_bounds__(128) void attn_kernel(
    const float* __restrict__ Q, const float* __restrict__ K,
    const float* __restrict__ V, float* __restrict__ O)
{
    __shared__ float Ks[32][64];
    __shared__ float Vs[32][64];
    __shared__ float Sl[32][128];

    const int tid = threadIdx.x;
    const int bh = blockIdx.y;           // b*16 + h
    const int b = bh >> 4, h = bh & 15;
    const int row = blockIdx.x * 128 + tid;

    const float* qp = Q + ((size_t)bh * NX + row) * HD;
    float q[64];
#pragma unroll
    for (int d = 0; d < 64; d += 4) {
        float4 v4 = *(const float4*)(qp + d);
        q[d] = v4.x; q[d + 1] = v4.y; q[d + 2] = v4.z; q[d + 3] = v4.w;
    }
    float acc[64];
#pragma unroll
    for (int d = 0; d < 64; ++d) acc[d] = 0.f;
    float mrun = -INFINITY, l = 0.f;

    const float* Kb = K + (size_t)bh * NC * HD;
    const float* Vb = V + (size_t)bh * NC * HD;

    for (int t0 = 0; t0 < NC; t0 += 32) {
        __syncthreads();
#pragma unroll
        for (int i = 0; i < 4; ++i) {
            const int e = tid + i * 128;      // 0..511
            const int kr = e >> 4, c4 = (e & 15) << 2;
            *(float4*)&Ks[kr][c4] = *(const float4*)(Kb + (size_t)(t0 + kr) * HD + c4);
            *(float4*)&Vs[kr][c4] = *(const float4*)(Vb + (size_t)(t0 + kr) * HD + c4);
        }
        __syncthreads();

        float tmax = mrun;
        for (int kk = 0; kk < 32; ++kk) {
            float d0 = 0.f, d1 = 0.f, d2 = 0.f, d3 = 0.f;
#pragma unroll
            for (int d = 0; d < 64; d += 4) {
                d0 += q[d + 0] * Ks[kk][d + 0];
                d1 += q[d + 1] * Ks[kk][d + 1];
                d2 += q[d + 2] * Ks[kk][d + 2];
                d3 += q[d + 3] * Ks[kk][d + 3];
            }
            const float s = ((d0 + d1) + (d2 + d3)) * 0.125f;
            Sl[kk][tid] = s;
            tmax = fmaxf(tmax, s);
        }
        const float alpha = __expf(mrun - tmax);  // first tile: exp(-inf)=0
        l *= alpha;
#pragma unroll
        for (int d = 0; d < 64; ++d) acc[d] *= alpha;
        for (int kk = 0; kk < 32; ++kk) {
            const float p = __expf(Sl[kk][tid] - tmax);
            l += p;
#pragma unroll
            for (int d = 0; d < 64; ++d) acc[d] += p * Vs[kk][d];
        }
        mrun = tmax;
    }

    const float inv = 1.f / l;
    float* op = O + ((size_t)b * NX + row) * DIMC + h * HD;  // (B, NX, D) layout
#pragma unroll
    for (int d = 0; d < 64; d += 4) {
        float4 v4 = make_float4(acc[d] * inv, acc[d + 1] * inv,
                                acc[d + 2] * inv, acc[d + 3] * inv);
        *(float4*)(op + d) = v4;
    }
}

// ---------------------------------------------------------------------------
extern "C" void kernel_launch(void* const* d_in, const int* in_sizes, int n_in,
                              void* d_out, int out_size, void* d_ws, size_t ws_size,
                              hipStream_t stream)
{
    const float* x     = (const float*)d_in[0];  // (4,1024,1024)
    const float* c     = (const float*)d_in[1];  // (4,2048,1024)
    const float* xpe   = (const float*)d_in[2];  // (1024,64)
    const float* cpe   = (const float*)d_in[3];  // (2048,64)
    const float* Wq    = (const float*)d_in[4];  // (1024,1024)
    const float* Wkv   = (const float*)d_in[5];  // (1024,2048)
    const float* Wproj = (const float*)d_in[6];  // (1024,1024)
    const float* bproj = (const float*)d_in[7];  // (1024,)

    float* out = (float*)d_out;
    float* ws  = (float*)d_ws;

    // d_out doubles as Q scratch (16 MB): written by gemm<0>, read by attn,
    // then fully overwritten by gemm<2>. ws needs 20M floats = 80 MB.
    float* Qw = out;                         // (B,H,NX,HD) = 4M floats
    float* Kw = ws;                          // (B,H,NC,HD) = 8M floats
    float* Vw = ws + (size_t)8 * 1024 * 1024;   // 8M floats
    float* Ow = ws + (size_t)16 * 1024 * 1024;  // (B,NX,D) = 4M floats

    dim3 blk(256);
    // Q = x @ Wq, + RoPE  (M=4096, N=1024, K=1024)
    gemm_fused<0><<<dim3(16, 64), blk, 0, stream>>>(x, Wq, xpe, nullptr, Qw, nullptr,
                                                    NB * NX, DIMC, DIMC);
    // KV = c @ Wkv, K+RoPE / V  (M=8192, N=2048, K=1024)
    gemm_fused<1><<<dim3(32, 128), blk, 0, stream>>>(c, Wkv, cpe, nullptr, Kw, Vw,
                                                     NB * NC, 2 * DIMC, DIMC);
    // attention: grid (NX/128, B*H)
    attn_kernel<<<dim3(NX / 128, NB * NHEAD), dim3(128), 0, stream>>>(Qw, Kw, Vw, Ow);
    // out = O @ Wproj + bproj  (M=4096, N=1024, K=1024)
    gemm_fused<2><<<dim3(16, 64), blk, 0, stream>>>(Ow, Wproj, nullptr, bproj, out, nullptr,
                                                    NB * NX, DIMC, DIMC);
}

// Round 2
// 869.758 us; speedup vs baseline: 2.4368x; 2.4368x over previous
//
#include <hip/hip_runtime.h>
#include <hip/hip_bf16.h>
#include <math.h>

// Shapes (fixed by the problem)
#define DIMC  1024
#define NHEAD 16
#define HD    64
#define NB    4
#define NX    1024
#define NC    2048

typedef __attribute__((ext_vector_type(8))) short short8;
typedef __attribute__((ext_vector_type(4))) float f32x4;

// ---------------------------------------------------------------------------
// Tiled fp32 GEMM, 64x64 tile, 256 threads, 4x4 micro-tile, K-tile 16.
// MODE 0: C = A@B, RoPE, *0.125 -> bf16 out0 laid out (B, H, NX, HD)
// MODE 1: C = A@B (N=2048). cols<1024: K + RoPE -> bf16 out0 (B,H,NC,HD);
//         cols>=1024: V -> bf16 out1 (B,H,NC,HD)
// MODE 2: C = A@B + bias -> fp32 out0 row-major (M, N)
// ---------------------------------------------------------------------------
template <int MODE>
__global__ __launch_bounds__(256) void gemm_fused(
    const float* __restrict__ A, const float* __restrict__ B,
    const float* __restrict__ pos, const float* __restrict__ bias,
    void* __restrict__ out0, void* __restrict__ out1,
    int M, int N, int K)
{
    __shared__ float As[16][68];   // A^T tile: As[k][m]
    __shared__ float Bs[16][64];   // B tile: Bs[k][n]
    __shared__ float Ct[64][66];   // raw result staging for RoPE pairing

    const int tid = threadIdx.x;
    const int tx = tid & 15, ty = tid >> 4;
    const int m0 = blockIdx.y * 64, n0 = blockIdx.x * 64;

    float acc[4][4];
#pragma unroll
    for (int i = 0; i < 4; ++i)
#pragma unroll
        for (int j = 0; j < 4; ++j) acc[i][j] = 0.f;

    const int arow = tid >> 2;          // 0..63
    const int ak4  = (tid & 3) << 2;    // 0,4,8,12
    const int bk   = tid >> 4;          // 0..15
    const int bn4  = (tid & 15) << 2;   // 0..60

    const float* Aptr = A + (size_t)(m0 + arow) * K + ak4;
    const float* Bptr = B + (size_t)bk * N + n0 + bn4;

    for (int k0 = 0; k0 < K; k0 += 16) {
        float4 av = *(const float4*)(Aptr + k0);
        float4 bv = *(const float4*)(Bptr + (size_t)k0 * N);
        As[ak4 + 0][arow] = av.x;
        As[ak4 + 1][arow] = av.y;
        As[ak4 + 2][arow] = av.z;
        As[ak4 + 3][arow] = av.w;
        *(float4*)&Bs[bk][bn4] = bv;
        __syncthreads();
#pragma unroll
        for (int kk = 0; kk < 16; ++kk) {
            float4 a = *(const float4*)&As[kk][ty << 2];
            float4 b = *(const float4*)&Bs[kk][tx << 2];
            acc[0][0] += a.x * b.x; acc[0][1] += a.x * b.y; acc[0][2] += a.x * b.z; acc[0][3] += a.x * b.w;
            acc[1][0] += a.y * b.x; acc[1][1] += a.y * b.y; acc[1][2] += a.y * b.z; acc[1][3] += a.y * b.w;
            acc[2][0] += a.z * b.x; acc[2][1] += a.z * b.y; acc[2][2] += a.z * b.z; acc[2][3] += a.z * b.w;
            acc[3][0] += a.w * b.x; acc[3][1] += a.w * b.y; acc[3][2] += a.w * b.z; acc[3][3] += a.w * b.w;
        }
        __syncthreads();
    }

    if (MODE == 2) {
        float* o = (float*)out0;
#pragma unroll
        for (int i = 0; i < 4; ++i) {
            const int m = m0 + (ty << 2) + i;
            float* op = o + (size_t)m * N + n0 + (tx << 2);
#pragma unroll
            for (int j = 0; j < 4; ++j)
                op[j] = acc[i][j] + bias[n0 + (tx << 2) + j];
        }
        return;
    }

    // stage raw tile so each thread can read its RoPE partner column (d ^ 32)
#pragma unroll
    for (int i = 0; i < 4; ++i)
#pragma unroll
        for (int j = 0; j < 4; ++j)
            Ct[(ty << 2) + i][(tx << 2) + j] = acc[i][j];
    __syncthreads();

    if (MODE == 0) {
        __hip_bfloat16* o0 = (__hip_bfloat16*)out0;
        const int h = n0 >> 6;  // N==1024, 64-wide tiles align with heads
#pragma unroll
        for (int i = 0; i < 4; ++i) {
            const int m = m0 + (ty << 2) + i;
            const int b = m >> 10, n = m & 1023;  // NX = 1024
#pragma unroll
            for (int j = 0; j < 4; ++j) {
                const int d = (tx << 2) + j;
                const float th  = pos[n * HD + d];
                const float val = Ct[(ty << 2) + i][d];
                const float pv  = Ct[(ty << 2) + i][d ^ 32];
                const float o = val * cosf(th) + (d < 32 ? -pv : pv) * sinf(th);
                // fold softmax scale 1/sqrt(64)=0.125 (exact in bf16)
                o0[(((size_t)(b * NHEAD + h)) * NX + n) * HD + d] = __float2bfloat16(o * 0.125f);
            }
        }
    } else {  // MODE 1
        __hip_bfloat16* o0 = (__hip_bfloat16*)out0;
        __hip_bfloat16* o1 = (__hip_bfloat16*)out1;
        const int pair = n0 >> 10;           // 0 = K, 1 = V (block-uniform)
        const int h = (n0 & 1023) >> 6;
#pragma unroll
        for (int i = 0; i < 4; ++i) {
            const int m = m0 + (ty << 2) + i;
            const int b = m >> 11, n = m & 2047;  // NC = 2048
#pragma unroll
            for (int j = 0; j < 4; ++j) {
                const int d = (tx << 2) + j;
                const float val = Ct[(ty << 2) + i][d];
                if (pair == 0) {
                    const float th = pos[n * HD + d];
                    const float pv = Ct[(ty << 2) + i][d ^ 32];
                    const float o = val * cosf(th) + (d < 32 ? -pv : pv) * sinf(th);
                    o0[(((size_t)(b * NHEAD + h)) * NC + n) * HD + d] = __float2bfloat16(o);
                } else {
                    o1[(((size_t)(b * NHEAD + h)) * NC + n) * HD + d] = __float2bfloat16(val);
                }
            }
        }
    }
}

// ---------------------------------------------------------------------------
// MFMA flash attention. Block = 256 threads (4 waves), 64 q-rows (16/wave),
// kv-tiles of 64. bf16 inputs (scale prefolded into Q), fp32 softmax state.
// Fragment convention (consistent for A and B loads, so any HW k-permutation
// cancels): row/col = lane&15, k = (lane>>4)*8 + i. C/D layout (HW-verified):
// col = lane&15, row = (lane>>4)*4 + reg.
// ---------------------------------------------------------------------------
__global__ __launch_bounds__(256) void attn_mfma(
    const __hip_bfloat16* __restrict__ Q, const __hip_bfloat16* __restrict__ K,
    const __hip_bfloat16* __restrict__ V, float* __restrict__ O)
{
    __shared__ __hip_bfloat16 Ks[64][72];  // [kv][hd], padded
    __shared__ __hip_bfloat16 Vt[64][72];  // [hd][kv ^ swz(d)], padded
    __shared__ __hip_bfloat16 Ps[64][72];  // [q][kv], per-wave-private rows

    const int tid  = threadIdx.x;
    const int w    = tid >> 6;
    const int lane = tid & 63;
    const int lr   = lane & 15;
    const int lg   = lane >> 4;

    const int bh = blockIdx.y;
    const int b  = bh >> 4, h = bh & 15;
    const int q0 = blockIdx.x * 64;

    // Q A-fragments in registers: row = lr, k = ks*32 + lg*8 + i
    const __hip_bfloat16* qbase = Q + ((size_t)bh * NX + q0 + w * 16 + lr) * HD + lg * 8;
    const short8 qf0 = *(const short8*)(qbase);
    const short8 qf1 = *(const short8*)(qbase + 32);

    f32x4 acc0 = {0.f,0.f,0.f,0.f}, acc1 = acc0, acc2 = acc0, acc3 = acc0;
    float mrun[4] = {-INFINITY, -INFINITY, -INFINITY, -INFINITY};
    float lsum[4] = {0.f, 0.f, 0.f, 0.f};

    const __hip_bfloat16* Kb = K + (size_t)bh * NC * HD;
    const __hip_bfloat16* Vb = V + (size_t)bh * NC * HD;

    for (int t0 = 0; t0 < NC; t0 += 64) {
        __syncthreads();
        // stage K (direct) and V (transposed + XOR col swizzle)
#pragma unroll
        for (int it = 0; it < 2; ++it) {
            const int c = tid + it * 256;        // 0..511
            const int row = c >> 3, off = (c & 7) << 3;
            *(int4*)&Ks[row][off] = *(const int4*)(Kb + (size_t)(t0 + row) * HD + off);
            int4 vv = *(const int4*)(Vb + (size_t)(t0 + row) * HD + off);
            const __hip_bfloat16* ve = (const __hip_bfloat16*)&vv;
#pragma unroll
            for (int j = 0; j < 8; ++j) {
                const int d = off + j;
                Vt[d][row ^ (((d >> 3) & 7) << 3)] = ve[j];
            }
        }
        __syncthreads();

        // S = Q K^T (scale already in Q). D: col=kv(lane&15), row=q(lg*4+r)
        f32x4 sc[4];
#pragma unroll
        for (int cb = 0; cb < 4; ++cb) {
            f32x4 a = {0.f,0.f,0.f,0.f};
            const short8 kf0 = *(const short8*)&Ks[cb * 16 + lr][lg * 8];
            const short8 kf1 = *(const short8*)&Ks[cb * 16 + lr][32 + lg * 8];
            a = __builtin_amdgcn_mfma_f32_16x16x32_bf16(qf0, kf0, a, 0, 0, 0);
            a = __builtin_amdgcn_mfma_f32_16x16x32_bf16(qf1, kf1, a, 0, 0, 0);
            sc[cb] = a;
        }

        // online softmax: row max over 4 col-blocks + 16 lanes
        float mnew[4];
#pragma unroll
        for (int r = 0; r < 4; ++r) {
            float v = fmaxf(fmaxf(sc[0][r], sc[1][r]), fmaxf(sc[2][r], sc[3][r]));
            v = fmaxf(v, __shfl_xor(v, 1));
            v = fmaxf(v, __shfl_xor(v, 2));
            v = fmaxf(v, __shfl_xor(v, 4));
            v = fmaxf(v, __shfl_xor(v, 8));
            mnew[r] = fmaxf(v, mrun[r]);
        }
        float alpha[4], psum[4];
#pragma unroll
        for (int r = 0; r < 4; ++r) {
            alpha[r] = __expf(mrun[r] - mnew[r]);   // first tile: exp(-inf)=0
            mrun[r] = mnew[r];
            psum[r] = 0.f;
        }
        // P = exp(S - m) -> bf16 in Ps (wave-private rows, no barrier needed)
#pragma unroll
        for (int cb = 0; cb < 4; ++cb) {
#pragma unroll
            for (int r = 0; r < 4; ++r) {
                const float p = __expf(sc[cb][r] - mnew[r]);
                psum[r] += p;
                Ps[w * 16 + lg * 4 + r][cb * 16 + lr] = __float2bfloat16(p);
            }
        }
#pragma unroll
        for (int r = 0; r < 4; ++r) {
            float v = psum[r];
            v += __shfl_xor(v, 1);
            v += __shfl_xor(v, 2);
            v += __shfl_xor(v, 4);
            v += __shfl_xor(v, 8);
            lsum[r] = lsum[r] * alpha[r] + v;
        }
#pragma unroll
        for (int r = 0; r < 4; ++r) {
            acc0[r] *= alpha[r]; acc1[r] *= alpha[r];
            acc2[r] *= alpha[r]; acc3[r] *= alpha[r];
        }

        // O += P V. A = P (row=q, k=kv), B = V (k=kv, col=d via Vt swizzle)
        {
            const short8 pf0 = *(const short8*)&Ps[w * 16 + lr][lg * 8];
            const short8 pf1 = *(const short8*)&Ps[w * 16 + lr][32 + lg * 8];
#pragma unroll
            for (int db = 0; db < 4; ++db) {
                const int d  = db * 16 + lr;
                const int sw = ((d >> 3) & 7) << 3;
                const short8 vf0 = *(const short8*)&Vt[d][(lg * 8) ^ sw];
                const short8 vf1 = *(const short8*)&Vt[d][(32 + lg * 8) ^ sw];
                f32x4 ao = (db == 0) ? acc0 : (db == 1) ? acc1 : (db == 2) ? acc2 : acc3;
                ao = __builtin_amdgcn_mfma_f32_16x16x32_bf16(pf0, vf0, ao, 0, 0, 0);
                ao = __builtin_amdgcn_mfma_f32_16x16x32_bf16(pf1, vf1, ao, 0, 0, 0);
                if (db == 0) acc0 = ao; else if (db == 1) acc1 = ao;
                else if (db == 2) acc2 = ao; else acc3 = ao;
            }
        }
    }

    // epilogue: O[q][d] = acc/l, layout (B, NX, DIMC)
    float* Ob = O + ((size_t)b * NX + q0 + w * 16) * DIMC + h * HD;
#pragma unroll
    for (int r = 0; r < 4; ++r) {
        const float inv = 1.f / lsum[r];
        float* op = Ob + (size_t)(lg * 4 + r) * DIMC;
        op[0 * 16 + lr] = acc0[r] * inv;
        op[1 * 16 + lr] = acc1[r] * inv;
        op[2 * 16 + lr] = acc2[r] * inv;
        op[3 * 16 + lr] = acc3[r] * inv;
    }
}

// ---------------------------------------------------------------------------
extern "C" void kernel_launch(void* const* d_in, const int* in_sizes, int n_in,
                              void* d_out, int out_size, void* d_ws, size_t ws_size,
                              hipStream_t stream)
{
    const float* x     = (const float*)d_in[0];  // (4,1024,1024)
    const float* c     = (const float*)d_in[1];  // (4,2048,1024)
    const float* xpe   = (const float*)d_in[2];  // (1024,64)
    const float* cpe   = (const float*)d_in[3];  // (2048,64)
    const float* Wq    = (const float*)d_in[4];  // (1024,1024)
    const float* Wkv   = (const float*)d_in[5];  // (1024,2048)
    const float* Wproj = (const float*)d_in[6];  // (1024,1024)
    const float* bproj = (const float*)d_in[7];  // (1024,)

    float* out = (float*)d_out;

    // d_out doubles as Q scratch (first 8 MB, bf16): written by gemm<0>,
    // read by attn, then fully overwritten by gemm<2>.
    __hip_bfloat16* Qw = (__hip_bfloat16*)d_out;                 // 4M bf16
    __hip_bfloat16* Kw = (__hip_bfloat16*)d_ws;                  // 8M bf16 = 16MB
    __hip_bfloat16* Vw = Kw + (size_t)8 * 1024 * 1024;           // 8M bf16 = 16MB
    float*          Ow = (float*)((char*)d_ws + (size_t)32 * 1024 * 1024);  // 4M f32

    dim3 blk(256);
    // Q = x @ Wq, + RoPE, *0.125, bf16  (M=4096, N=1024, K=1024)
    gemm_fused<0><<<dim3(16, 64), blk, 0, stream>>>(x, Wq, xpe, nullptr, Qw, nullptr,
                                                    NB * NX, DIMC, DIMC);
    // KV = c @ Wkv, K+RoPE / V, bf16  (M=8192, N=2048, K=1024)
    gemm_fused<1><<<dim3(32, 128), blk, 0, stream>>>(c, Wkv, cpe, nullptr, Kw, Vw,
                                                     NB * NC, 2 * DIMC, DIMC);
    // attention: grid (NX/64, B*H)
    attn_mfma<<<dim3(NX / 64, NB * NHEAD), dim3(256), 0, stream>>>(Qw, Kw, Vw, Ow);
    // out = O @ Wproj + bproj  (M=4096, N=1024, K=1024)
    gemm_fused<2><<<dim3(16, 64), blk, 0, stream>>>(Ow, Wproj, nullptr, bproj, out, nullptr,
                                                    NB * NX, DIMC, DIMC);
}

// Round 3
// 273.216 us; speedup vs baseline: 7.7573x; 3.1834x over previous
//
#include <hip/hip_runtime.h>
#include <math.h>

// Shapes (fixed by the problem)
#define DIMC  1024
#define NHEAD 16
#define HD    64
#define NB    4
#define NX    1024
#define NC    2048
#define KD    1024

typedef _Float16 half_t;
typedef __attribute__((ext_vector_type(8))) _Float16 h8;
typedef __attribute__((ext_vector_type(4))) float f32x4;

__device__ __forceinline__ void gload_lds16(const half_t* g, half_t* l) {
    __builtin_amdgcn_global_load_lds(
        (__attribute__((address_space(1))) void*)(g),
        (__attribute__((address_space(3))) void*)(l), 16, 0, 0);
}

// ---------------------------------------------------------------------------
// fp32 -> fp16 elementwise convert (8 elems/thread)
// ---------------------------------------------------------------------------
__global__ __launch_bounds__(256) void cvt16(const float* __restrict__ s,
                                             half_t* __restrict__ d, int n)
{
    const int i = (blockIdx.x * 256 + threadIdx.x) * 8;
    if (i >= n) return;
    float4 a = *(const float4*)(s + i);
    float4 b = *(const float4*)(s + i + 4);
    h8 o;
    o[0] = (half_t)a.x; o[1] = (half_t)a.y; o[2] = (half_t)a.z; o[3] = (half_t)a.w;
    o[4] = (half_t)b.x; o[5] = (half_t)b.y; o[6] = (half_t)b.z; o[7] = (half_t)b.w;
    *(h8*)(d + i) = o;
}

// ---------------------------------------------------------------------------
// W (KD x N fp32, row-major) -> Wt (N x KD fp16, row-major)  [64x64 tiles]
// ---------------------------------------------------------------------------
__global__ __launch_bounds__(256) void wtrans(const float* __restrict__ W,
                                              half_t* __restrict__ Wt, int N)
{
    __shared__ half_t T[64][72];
    const int t = threadIdx.x;
    const int k0 = blockIdx.y * 64, n0 = blockIdx.x * 64;
    const int kr = t >> 2, c0 = (t & 3) << 4;
    const float* src = W + (size_t)(k0 + kr) * N + n0 + c0;
#pragma unroll
    for (int j = 0; j < 16; j += 4) {
        float4 v = *(const float4*)(src + j);
        T[c0 + j + 0][kr] = (half_t)v.x;
        T[c0 + j + 1][kr] = (half_t)v.y;
        T[c0 + j + 2][kr] = (half_t)v.z;
        T[c0 + j + 3][kr] = (half_t)v.w;
    }
    __syncthreads();
    const int nr = t >> 2, kc = (t & 3) << 4;
    half_t* dst = Wt + (size_t)(n0 + nr) * KD + k0 + kc;
    *(int4*)dst       = *(const int4*)&T[nr][kc];
    *(int4*)(dst + 8) = *(const int4*)&T[nr][kc + 8];
}

// ---------------------------------------------------------------------------
// fp16 MFMA GEMM: C(MxN) = A(MxK) @ Bt(NxK)^T, fp32 accum.
// 128x128 tile, 4 waves (2x2, 64x64/wave), BK=64, single-buffer LDS,
// global_load_lds(16B) with XOR-swizzled source (slot ^= row&7), swizzled
// ds_read_b128 fragment reads (2-way bank aliasing = free).
// MODE 0: RoPE(xpe) * 0.125 -> fp16 out0 (B,H,NX,HD)
// MODE 1: n<1024: RoPE(cpe) -> fp16 out0 (B,H,NC,HD); n>=1024: fp16 out1
// MODE 2: + bias -> fp32 out0 row-major (M, DIMC)
// ---------------------------------------------------------------------------
template <int MODE>
__global__ __launch_bounds__(256) void hgemm(
    const half_t* __restrict__ Ag, const half_t* __restrict__ Bt,
    const float* __restrict__ pos, const float* __restrict__ bias,
    void* __restrict__ out0, void* __restrict__ out1, int M, int N)
{
    __shared__ half_t As[8192];   // 128 rows x 64 cols (8 slots of 8 fp16)
    __shared__ half_t Bs[8192];

    const int tid = threadIdx.x;
    const int w = tid >> 6, lane = tid & 63;
    const int lr = lane & 15, lg = lane >> 4;
    const int wr = w >> 1, wc = w & 1;
    const int m0 = blockIdx.y * 128, n0 = blockIdx.x * 128;

    f32x4 acc[4][4];
#pragma unroll
    for (int i = 0; i < 4; ++i)
#pragma unroll
        for (int j = 0; j < 4; ++j) acc[i][j] = f32x4{0.f, 0.f, 0.f, 0.f};

    // staging: linear LDS byte L = c*4096 + w*1024 + lane*16; slot holds
    // global col-block (slot ^ (row&7))  -> read with the same XOR.
    size_t gA[4], gB[4];
    int loff[4];
#pragma unroll
    for (int c = 0; c < 4; ++c) {
        const int L = c * 4096 + w * 1024 + lane * 16;
        const int row = L >> 7;
        const int ss = ((L >> 4) & 7) ^ (row & 7);
        gA[c] = (size_t)(m0 + row) * KD + ss * 8;
        gB[c] = (size_t)(n0 + row) * KD + ss * 8;
        loff[c] = c * 2048 + w * 512;
    }

    for (int k0 = 0; k0 < KD; k0 += 64) {
#pragma unroll
        for (int c = 0; c < 4; ++c) {
            gload_lds16(Ag + gA[c] + k0, As + loff[c]);
            gload_lds16(Bt + gB[c] + k0, Bs + loff[c]);
        }
        __syncthreads();
#pragma unroll
        for (int kc = 0; kc < 2; ++kc) {
            h8 af[4], bf[4];
#pragma unroll
            for (int mi = 0; mi < 4; ++mi) {
                const int r = wr * 64 + mi * 16 + lr;
                af[mi] = *(const h8*)&As[r * 64 + (((kc * 4 + lg) ^ (r & 7)) << 3)];
            }
#pragma unroll
            for (int ni = 0; ni < 4; ++ni) {
                const int r = wc * 64 + ni * 16 + lr;
                bf[ni] = *(const h8*)&Bs[r * 64 + (((kc * 4 + lg) ^ (r & 7)) << 3)];
            }
#pragma unroll
            for (int mi = 0; mi < 4; ++mi)
#pragma unroll
                for (int ni = 0; ni < 4; ++ni)
                    acc[mi][ni] = __builtin_amdgcn_mfma_f32_16x16x32_f16(
                        af[mi], bf[ni], acc[mi][ni], 0, 0, 0);
        }
        __syncthreads();
    }

    // C/D layout: row = base + lg*4 + r, col = base + lr  (HW-verified)
    if (MODE == 2) {
        float* o = (float*)out0;
#pragma unroll
        for (int ni = 0; ni < 4; ++ni) {
            const int col = n0 + wc * 64 + ni * 16 + lr;
            const float bv = bias[col];
#pragma unroll
            for (int mi = 0; mi < 4; ++mi)
#pragma unroll
                for (int r = 0; r < 4; ++r) {
                    const int row = m0 + wr * 64 + mi * 16 + lg * 4 + r;
                    o[(size_t)row * DIMC + col] = acc[mi][ni][r] + bv;
                }
        }
        return;
    }

    if (MODE == 0) {
        half_t* Qw = (half_t*)out0;
        const int h = (n0 >> 6) + wc;   // tile covers 2 heads, wc picks one
#pragma unroll
        for (int mi = 0; mi < 4; ++mi)
#pragma unroll
            for (int r = 0; r < 4; ++r) {
                const int row = m0 + wr * 64 + mi * 16 + lg * 4 + r;
                const int bb = row >> 10, nn = row & (NX - 1);
                const float* pr = pos + nn * HD;
                half_t* op = Qw + (((size_t)(bb * NHEAD + h)) * NX + nn) * HD;
#pragma unroll
                for (int ni = 0; ni < 4; ++ni) {
                    const int d = ni * 16 + lr;
                    float sn, cs;
                    __sincosf(pr[d], &sn, &cs);
                    const float val = acc[mi][ni][r];
                    const float pv  = acc[mi][ni ^ 2][r];   // d ^ 32 partner
                    op[d] = (half_t)((val * cs + (ni < 2 ? -pv : pv) * sn) * 0.125f);
                }
            }
    } else {  // MODE 1
        const bool isK = (n0 < DIMC);
        const int h = ((n0 & (DIMC - 1)) >> 6) + wc;
        half_t* Kw = (half_t*)out0;
        half_t* Vw = (half_t*)out1;
#pragma unroll
        for (int mi = 0; mi < 4; ++mi)
#pragma unroll
            for (int r = 0; r < 4; ++r) {
                const int row = m0 + wr * 64 + mi * 16 + lg * 4 + r;
                const int bb = row >> 11, nn = row & (NC - 1);
                const size_t obase = (((size_t)(bb * NHEAD + h)) * NC + nn) * HD;
                const float* pr = pos + nn * HD;
#pragma unroll
                for (int ni = 0; ni < 4; ++ni) {
                    const int d = ni * 16 + lr;
                    const float val = acc[mi][ni][r];
                    if (isK) {
                        float sn, cs;
                        __sincosf(pr[d], &sn, &cs);
                        const float pv = acc[mi][ni ^ 2][r];
                        Kw[obase + d] = (half_t)(val * cs + (ni < 2 ? -pv : pv) * sn);
                    } else {
                        Vw[obase + d] = (half_t)val;
                    }
                }
            }
    }
}

// ---------------------------------------------------------------------------
// MFMA flash attention (fp16). Block = 4 waves, 64 q-rows (16/wave),
// kv-tiles of 64. Scale prefolded into Q. fp32 softmax state.
// ---------------------------------------------------------------------------
__global__ __launch_bounds__(256) void attn_mfma(
    const half_t* __restrict__ Q, const half_t* __restrict__ K,
    const half_t* __restrict__ V, half_t* __restrict__ O)
{
    __shared__ half_t Ks[64][72];  // [kv][hd]
    __shared__ half_t Vt[64][72];  // [hd][kv ^ swz(d)]
    __shared__ half_t Ps[64][72];  // [q][kv], wave-private rows

    const int tid  = threadIdx.x;
    const int w    = tid >> 6;
    const int lane = tid & 63;
    const int lr   = lane & 15;
    const int lg   = lane >> 4;

    const int bh = blockIdx.y;
    const int b  = bh >> 4, h = bh & 15;
    const int q0 = blockIdx.x * 64;

    const half_t* qbase = Q + ((size_t)bh * NX + q0 + w * 16 + lr) * HD + lg * 8;
    const h8 qf0 = *(const h8*)(qbase);
    const h8 qf1 = *(const h8*)(qbase + 32);

    f32x4 acc0 = {0.f,0.f,0.f,0.f}, acc1 = acc0, acc2 = acc0, acc3 = acc0;
    float mrun[4] = {-INFINITY, -INFINITY, -INFINITY, -INFINITY};
    float lsum[4] = {0.f, 0.f, 0.f, 0.f};

    const half_t* Kb = K + (size_t)bh * NC * HD;
    const half_t* Vb = V + (size_t)bh * NC * HD;

    for (int t0 = 0; t0 < NC; t0 += 64) {
        __syncthreads();
#pragma unroll
        for (int it = 0; it < 2; ++it) {
            const int cc = tid + it * 256;
            const int row = cc >> 3, off = (cc & 7) << 3;
            *(int4*)&Ks[row][off] = *(const int4*)(Kb + (size_t)(t0 + row) * HD + off);
            int4 vv = *(const int4*)(Vb + (size_t)(t0 + row) * HD + off);
            const half_t* ve = (const half_t*)&vv;
#pragma unroll
            for (int j = 0; j < 8; ++j) {
                const int d = off + j;
                Vt[d][row ^ (((d >> 3) & 7) << 3)] = ve[j];
            }
        }
        __syncthreads();

        f32x4 sc[4];
#pragma unroll
        for (int cb = 0; cb < 4; ++cb) {
            f32x4 a = {0.f,0.f,0.f,0.f};
            const h8 kf0 = *(const h8*)&Ks[cb * 16 + lr][lg * 8];
            const h8 kf1 = *(const h8*)&Ks[cb * 16 + lr][32 + lg * 8];
            a = __builtin_amdgcn_mfma_f32_16x16x32_f16(qf0, kf0, a, 0, 0, 0);
            a = __builtin_amdgcn_mfma_f32_16x16x32_f16(qf1, kf1, a, 0, 0, 0);
            sc[cb] = a;
        }

        float mnew[4];
#pragma unroll
        for (int r = 0; r < 4; ++r) {
            float v = fmaxf(fmaxf(sc[0][r], sc[1][r]), fmaxf(sc[2][r], sc[3][r]));
            v = fmaxf(v, __shfl_xor(v, 1));
            v = fmaxf(v, __shfl_xor(v, 2));
            v = fmaxf(v, __shfl_xor(v, 4));
            v = fmaxf(v, __shfl_xor(v, 8));
            mnew[r] = fmaxf(v, mrun[r]);
        }
        float alpha[4], psum[4];
#pragma unroll
        for (int r = 0; r < 4; ++r) {
            alpha[r] = __expf(mrun[r] - mnew[r]);
            mrun[r] = mnew[r];
            psum[r] = 0.f;
        }
#pragma unroll
        for (int cb = 0; cb < 4; ++cb) {
#pragma unroll
            for (int r = 0; r < 4; ++r) {
                const float p = __expf(sc[cb][r] - mnew[r]);
                psum[r] += p;
                Ps[w * 16 + lg * 4 + r][cb * 16 + lr] = (half_t)p;
            }
        }
#pragma unroll
        for (int r = 0; r < 4; ++r) {
            float v = psum[r];
            v += __shfl_xor(v, 1);
            v += __shfl_xor(v, 2);
            v += __shfl_xor(v, 4);
            v += __shfl_xor(v, 8);
            lsum[r] = lsum[r] * alpha[r] + v;
        }
#pragma unroll
        for (int r = 0; r < 4; ++r) {
            acc0[r] *= alpha[r]; acc1[r] *= alpha[r];
            acc2[r] *= alpha[r]; acc3[r] *= alpha[r];
        }

        {
            const h8 pf0 = *(const h8*)&Ps[w * 16 + lr][lg * 8];
            const h8 pf1 = *(const h8*)&Ps[w * 16 + lr][32 + lg * 8];
#pragma unroll
            for (int db = 0; db < 4; ++db) {
                const int d  = db * 16 + lr;
                const int sw = ((d >> 3) & 7) << 3;
                const h8 vf0 = *(const h8*)&Vt[d][(lg * 8) ^ sw];
                const h8 vf1 = *(const h8*)&Vt[d][(32 + lg * 8) ^ sw];
                f32x4 ao = (db == 0) ? acc0 : (db == 1) ? acc1 : (db == 2) ? acc2 : acc3;
                ao = __builtin_amdgcn_mfma_f32_16x16x32_f16(pf0, vf0, ao, 0, 0, 0);
                ao = __builtin_amdgcn_mfma_f32_16x16x32_f16(pf1, vf1, ao, 0, 0, 0);
                if (db == 0) acc0 = ao; else if (db == 1) acc1 = ao;
                else if (db == 2) acc2 = ao; else acc3 = ao;
            }
        }
    }

    // O fp16, layout (B, NX, DIMC) -> feeds proj GEMM as A
    half_t* Ob = O + ((size_t)b * NX + q0 + w * 16) * DIMC + h * HD;
#pragma unroll
    for (int r = 0; r < 4; ++r) {
        const float inv = 1.f / lsum[r];
        half_t* op = Ob + (size_t)(lg * 4 + r) * DIMC;
        op[0 * 16 + lr] = (half_t)(acc0[r] * inv);
        op[1 * 16 + lr] = (half_t)(acc1[r] * inv);
        op[2 * 16 + lr] = (half_t)(acc2[r] * inv);
        op[3 * 16 + lr] = (half_t)(acc3[r] * inv);
    }
}

// ---------------------------------------------------------------------------
extern "C" void kernel_launch(void* const* d_in, const int* in_sizes, int n_in,
                              void* d_out, int out_size, void* d_ws, size_t ws_size,
                              hipStream_t stream)
{
    const float* x     = (const float*)d_in[0];
    const float* c     = (const float*)d_in[1];
    const float* xpe   = (const float*)d_in[2];
    const float* cpe   = (const float*)d_in[3];
    const float* Wq    = (const float*)d_in[4];
    const float* Wkv   = (const float*)d_in[5];
    const float* Wproj = (const float*)d_in[6];
    const float* bproj = (const float*)d_in[7];

    char* wsb = (char*)d_ws;
    half_t* xh  = (half_t*)(wsb);                          // 8 MB
    half_t* ch  = (half_t*)(wsb + ((size_t)8  << 20));     // 16 MB
    half_t* Wqt = (half_t*)(wsb + ((size_t)24 << 20));     // 2 MB
    half_t* Wkt = (half_t*)(wsb + ((size_t)26 << 20));     // 4 MB
    half_t* Wpt = (half_t*)(wsb + ((size_t)30 << 20));     // 2 MB
    half_t* Kw  = (half_t*)(wsb + ((size_t)32 << 20));     // 16 MB
    half_t* Vw  = (half_t*)(wsb + ((size_t)48 << 20));     // 16 MB
    half_t* Ow  = (half_t*)(wsb + ((size_t)64 << 20));     // 8 MB
    half_t* Qw  = (half_t*)d_out;   // 8 MB of the 16 MB out buffer; attn
                                    // consumes it before hgemm<2> overwrites.

    cvt16<<<2048, 256, 0, stream>>>(x, xh, NB * NX * DIMC);
    cvt16<<<4096, 256, 0, stream>>>(c, ch, NB * NC * DIMC);
    wtrans<<<dim3(16, 16), 256, 0, stream>>>(Wq, Wqt, DIMC);
    wtrans<<<dim3(32, 16), 256, 0, stream>>>(Wkv, Wkt, 2 * DIMC);
    wtrans<<<dim3(16, 16), 256, 0, stream>>>(Wproj, Wpt, DIMC);

    hgemm<0><<<dim3(8, 32), 256, 0, stream>>>(xh, Wqt, xpe, nullptr,
                                              Qw, nullptr, NB * NX, DIMC);
    hgemm<1><<<dim3(16, 64), 256, 0, stream>>>(ch, Wkt, cpe, nullptr,
                                               Kw, Vw, NB * NC, 2 * DIMC);
    attn_mfma<<<dim3(16, 64), 256, 0, stream>>>(Qw, Kw, Vw, Ow);
    hgemm<2><<<dim3(8, 32), 256, 0, stream>>>(Ow, Wpt, nullptr, bproj,
                                              (float*)d_out, nullptr, NB * NX, DIMC);
}

// Round 4
// 224.746 us; speedup vs baseline: 9.4303x; 1.2157x over previous
//
#include <hip/hip_runtime.h>
#include <math.h>

// Shapes (fixed by the problem)
#define DIMC  1024
#define NHEAD 16
#define HD    64
#define NB    4
#define NX    1024
#define NC    2048
#define KD    1024

typedef _Float16 half_t;
typedef __attribute__((ext_vector_type(8))) _Float16 h8;
typedef __attribute__((ext_vector_type(4))) _Float16 h4;
typedef __attribute__((ext_vector_type(4))) float f32x4;

__device__ __forceinline__ void gload_lds16(const half_t* g, half_t* l) {
    __builtin_amdgcn_global_load_lds(
        (__attribute__((address_space(1))) void*)(g),
        (__attribute__((address_space(3))) void*)(l), 16, 0, 0);
}

// ---------------------------------------------------------------------------
// fp32 -> fp16 elementwise convert (8 elems/thread)
// ---------------------------------------------------------------------------
__global__ __launch_bounds__(256) void cvt16(const float* __restrict__ s,
                                             half_t* __restrict__ d, int n)
{
    const int i = (blockIdx.x * 256 + threadIdx.x) * 8;
    if (i >= n) return;
    float4 a = *(const float4*)(s + i);
    float4 b = *(const float4*)(s + i + 4);
    h8 o;
    o[0] = (half_t)a.x; o[1] = (half_t)a.y; o[2] = (half_t)a.z; o[3] = (half_t)a.w;
    o[4] = (half_t)b.x; o[5] = (half_t)b.y; o[6] = (half_t)b.z; o[7] = (half_t)b.w;
    *(h8*)(d + i) = o;
}

// ---------------------------------------------------------------------------
// W (KD x N fp32, row-major) -> Wt (N x KD fp16, row-major)  [64x64 tiles]
// ---------------------------------------------------------------------------
__global__ __launch_bounds__(256) void wtrans(const float* __restrict__ W,
                                              half_t* __restrict__ Wt, int N)
{
    __shared__ half_t T[64][72];
    const int t = threadIdx.x;
    const int k0 = blockIdx.y * 64, n0 = blockIdx.x * 64;
    const int kr = t >> 2, c0 = (t & 3) << 4;
    const float* src = W + (size_t)(k0 + kr) * N + n0 + c0;
#pragma unroll
    for (int j = 0; j < 16; j += 4) {
        float4 v = *(const float4*)(src + j);
        T[c0 + j + 0][kr] = (half_t)v.x;
        T[c0 + j + 1][kr] = (half_t)v.y;
        T[c0 + j + 2][kr] = (half_t)v.z;
        T[c0 + j + 3][kr] = (half_t)v.w;
    }
    __syncthreads();
    const int nr = t >> 2, kc = (t & 3) << 4;
    half_t* dst = Wt + (size_t)(n0 + nr) * KD + k0 + kc;
    *(int4*)dst       = *(const int4*)&T[nr][kc];
    *(int4*)(dst + 8) = *(const int4*)&T[nr][kc + 8];
}

// ---------------------------------------------------------------------------
// fp16 MFMA GEMM: C(MxN) = A(MxK) @ Bt(NxK)^T, fp32 accum.
// 128x128 tile, 4 waves (2x2), BK=64, global_load_lds(16B), XOR-swizzled LDS.
// MODE 0: RoPE(xpe) * 0.125 -> fp16 out0 (B,H,NX,HD)
// MODE 1: n<1024: RoPE(cpe) -> fp16 K in swizzled-tile image layout;
//         n>=1024: fp16 V^T in swizzled-tile image layout (see attn_mfma)
// MODE 2: + bias -> fp32 out0 row-major (M, DIMC)
// ---------------------------------------------------------------------------
template <int MODE>
__global__ __launch_bounds__(256) void hgemm(
    const half_t* __restrict__ Ag, const half_t* __restrict__ Bt,
    const float* __restrict__ pos, const float* __restrict__ bias,
    void* __restrict__ out0, void* __restrict__ out1, int M, int N)
{
    __shared__ half_t As[8192];   // 128 rows x 64 cols (8 slots of 8 fp16)
    __shared__ half_t Bs[8192];

    const int tid = threadIdx.x;
    const int w = tid >> 6, lane = tid & 63;
    const int lr = lane & 15, lg = lane >> 4;
    const int wr = w >> 1, wc = w & 1;
    const int m0 = blockIdx.y * 128, n0 = blockIdx.x * 128;

    f32x4 acc[4][4];
#pragma unroll
    for (int i = 0; i < 4; ++i)
#pragma unroll
        for (int j = 0; j < 4; ++j) acc[i][j] = f32x4{0.f, 0.f, 0.f, 0.f};

    size_t gA[4], gB[4];
    int loff[4];
#pragma unroll
    for (int c = 0; c < 4; ++c) {
        const int L = c * 4096 + w * 1024 + lane * 16;
        const int row = L >> 7;
        const int ss = ((L >> 4) & 7) ^ (row & 7);
        gA[c] = (size_t)(m0 + row) * KD + ss * 8;
        gB[c] = (size_t)(n0 + row) * KD + ss * 8;
        loff[c] = c * 2048 + w * 512;
    }

    for (int k0 = 0; k0 < KD; k0 += 64) {
#pragma unroll
        for (int c = 0; c < 4; ++c) {
            gload_lds16(Ag + gA[c] + k0, As + loff[c]);
            gload_lds16(Bt + gB[c] + k0, Bs + loff[c]);
        }
        __syncthreads();
#pragma unroll
        for (int kc = 0; kc < 2; ++kc) {
            h8 af[4], bf[4];
#pragma unroll
            for (int mi = 0; mi < 4; ++mi) {
                const int r = wr * 64 + mi * 16 + lr;
                af[mi] = *(const h8*)&As[r * 64 + (((kc * 4 + lg) ^ (r & 7)) << 3)];
            }
#pragma unroll
            for (int ni = 0; ni < 4; ++ni) {
                const int r = wc * 64 + ni * 16 + lr;
                bf[ni] = *(const h8*)&Bs[r * 64 + (((kc * 4 + lg) ^ (r & 7)) << 3)];
            }
#pragma unroll
            for (int mi = 0; mi < 4; ++mi)
#pragma unroll
                for (int ni = 0; ni < 4; ++ni)
                    acc[mi][ni] = __builtin_amdgcn_mfma_f32_16x16x32_f16(
                        af[mi], bf[ni], acc[mi][ni], 0, 0, 0);
        }
        __syncthreads();
    }

    // C/D layout: row = base + lg*4 + r, col = base + lr  (HW-verified)
    if (MODE == 2) {
        float* o = (float*)out0;
#pragma unroll
        for (int ni = 0; ni < 4; ++ni) {
            const int col = n0 + wc * 64 + ni * 16 + lr;
            const float bv = bias[col];
#pragma unroll
            for (int mi = 0; mi < 4; ++mi)
#pragma unroll
                for (int r = 0; r < 4; ++r) {
                    const int row = m0 + wr * 64 + mi * 16 + lg * 4 + r;
                    o[(size_t)row * DIMC + col] = acc[mi][ni][r] + bv;
                }
        }
        return;
    }

    if (MODE == 0) {
        half_t* Qw = (half_t*)out0;
        const int h = (n0 >> 6) + wc;   // tile covers 2 heads, wc picks one
#pragma unroll
        for (int mi = 0; mi < 4; ++mi)
#pragma unroll
            for (int r = 0; r < 4; ++r) {
                const int row = m0 + wr * 64 + mi * 16 + lg * 4 + r;
                const int bb = row >> 10, nn = row & (NX - 1);
                const float* pr = pos + nn * HD;
                half_t* op = Qw + (((size_t)(bb * NHEAD + h)) * NX + nn) * HD;
#pragma unroll
                for (int ni = 0; ni < 4; ++ni) {
                    const int d = ni * 16 + lr;
                    float sn, cs;
                    __sincosf(pr[d], &sn, &cs);
                    const float val = acc[mi][ni][r];
                    const float pv  = acc[mi][ni ^ 2][r];   // d ^ 32 partner
                    op[d] = (half_t)((val * cs + (ni < 2 ? -pv : pv) * sn) * 0.125f);
                }
            }
    } else {  // MODE 1: K/V in swizzled LDS-tile-image global layouts
        const bool isK = (n0 < DIMC);
        const int h = ((n0 & (DIMC - 1)) >> 6) + wc;
        half_t* Kw = (half_t*)out0;
        half_t* Vw = (half_t*)out1;
#pragma unroll
        for (int mi = 0; mi < 4; ++mi)
#pragma unroll
            for (int r = 0; r < 4; ++r) {
                const int row = m0 + wr * 64 + mi * 16 + lg * 4 + r;
                const int bb = row >> 11, nn = row & (NC - 1);
                const int tt = nn >> 6, rr = nn & 63;
                const size_t tbase = ((size_t)(bb * NHEAD + h) * 32 + tt) * 4096;
                const float* pr = pos + nn * HD;
#pragma unroll
                for (int ni = 0; ni < 4; ++ni) {
                    const int d = ni * 16 + lr;
                    const float val = acc[mi][ni][r];
                    if (isK) {
                        float sn, cs;
                        __sincosf(pr[d], &sn, &cs);
                        const float pv = acc[mi][ni ^ 2][r];
                        // K image: (row=rr, col=d): rr*64 + ((d>>3 ^ rr&7)<<3) + (d&7)
                        Kw[tbase + rr * 64 + ((((d >> 3) ^ (rr & 7)) << 3) | (d & 7))] =
                            (half_t)(val * cs + (ni < 2 ? -pv : pv) * sn);
                    } else {
                        // V^T image: (row=d, col=rr): d*64 + ((rr>>3 ^ d&7)<<3) + (rr&7)
                        Vw[tbase + d * 64 + ((((rr >> 3) ^ (d & 7)) << 3) | (rr & 7))] =
                            (half_t)val;
                    }
                }
            }
    }
}

// ---------------------------------------------------------------------------
// Swapped-operand MFMA flash attention (fp16). 4 waves, 64 q-rows (16/wave),
// kv-tiles of 64, double-buffered K/V staged by global_load_lds from the
// pre-swizzled global tile images. S^T = K Q^T so softmax is lane-local.
// ---------------------------------------------------------------------------
__global__ __launch_bounds__(256) void attn_mfma(
    const half_t* __restrict__ Q, const half_t* __restrict__ Kg,
    const half_t* __restrict__ Vg, half_t* __restrict__ O)
{
    __shared__ half_t Ks[2][4096];   // swizzled K tile image [kv][d]
    __shared__ half_t Vs[2][4096];   // swizzled V^T tile image [d][kv]
    __shared__ half_t Ps[4096];      // swizzled P [q][kv], wave-private rows

    const int tid = threadIdx.x;
    const int w = tid >> 6, lane = tid & 63;
    const int lr = lane & 15, lg = lane >> 4;
    const int e7 = lr & 7;

    // XCD swizzle: 1024 blocks -> 8 chunks of 128; 16 q-blocks/bh stay on-XCD
    const int sid = (blockIdx.x & 7) * 128 + (blockIdx.x >> 3);
    const int bh = sid >> 4;
    const int q0 = (sid & 15) * 64;
    const int b = bh >> 4, h = bh & 15;

    // Q fragments (q = q0 + w*16 + lr), 0.125 scale prefolded by hgemm<0>
    const half_t* qbase = Q + ((size_t)bh * NX + q0 + w * 16 + lr) * HD + lg * 8;
    const h8 qf0 = *(const h8*)(qbase);
    const h8 qf1 = *(const h8*)(qbase + 32);

    f32x4 acc[4];
#pragma unroll
    for (int i = 0; i < 4; ++i) acc[i] = f32x4{0.f, 0.f, 0.f, 0.f};
    float mrun = -INFINITY, lsum = 0.f;

    const half_t* Kt = Kg + (size_t)bh * 32 * 4096;
    const half_t* Vt = Vg + (size_t)bh * 32 * 4096;
    const int so = w * 512 + lane * 8;   // per-lane half offset within tile

#define STAGE(bi, t) do {                                           \
        const half_t* kg_ = Kt + (size_t)(t) * 4096;                \
        const half_t* vg_ = Vt + (size_t)(t) * 4096;                \
        gload_lds16(kg_ + so,        &Ks[bi][w * 512]);             \
        gload_lds16(kg_ + 2048 + so, &Ks[bi][2048 + w * 512]);      \
        gload_lds16(vg_ + so,        &Vs[bi][w * 512]);             \
        gload_lds16(vg_ + 2048 + so, &Vs[bi][2048 + w * 512]);      \
    } while (0)

    STAGE(0, 0);
    __syncthreads();

    const int rowq = w * 16 + lr;        // this lane's q row (local)

    for (int t = 0; t < NC / 64; ++t) {
        const int cur = t & 1;
        if (t + 1 < NC / 64) STAGE(cur ^ 1, t + 1);

        // S^T = K Q^T : A=K rows (kv), B=Q (col=q). Lane: q=lr fixed,
        // scores at kv = cb*16 + lg*4 + r.
        f32x4 sc[4];
        __builtin_amdgcn_s_setprio(1);
#pragma unroll
        for (int cb = 0; cb < 4; ++cb) {
            const int r = cb * 16 + lr;
            const h8 kf0 = *(const h8*)&Ks[cur][r * 64 + ((lg ^ e7) << 3)];
            const h8 kf1 = *(const h8*)&Ks[cur][r * 64 + (((4 + lg) ^ e7) << 3)];
            f32x4 a = {0.f, 0.f, 0.f, 0.f};
            a = __builtin_amdgcn_mfma_f32_16x16x32_f16(kf0, qf0, a, 0, 0, 0);
            a = __builtin_amdgcn_mfma_f32_16x16x32_f16(kf1, qf1, a, 0, 0, 0);
            sc[cb] = a;
        }
        __builtin_amdgcn_s_setprio(0);

        // lane-local softmax over 16 scores + 2 cross-lg shuffles
        float m16 = sc[0][0];
#pragma unroll
        for (int cb = 0; cb < 4; ++cb)
#pragma unroll
            for (int r = 0; r < 4; ++r) m16 = fmaxf(m16, sc[cb][r]);
        m16 = fmaxf(m16, __shfl_xor(m16, 16));
        m16 = fmaxf(m16, __shfl_xor(m16, 32));
        const float mnew = fmaxf(mrun, m16);
        const float alpha = __expf(mrun - mnew);
        mrun = mnew;

        float p[4][4];
        float ps = 0.f;
#pragma unroll
        for (int cb = 0; cb < 4; ++cb)
#pragma unroll
            for (int r = 0; r < 4; ++r) {
                p[cb][r] = __expf(sc[cb][r] - mnew);
                ps += p[cb][r];
            }
        ps += __shfl_xor(ps, 16);
        ps += __shfl_xor(ps, 32);
        lsum = lsum * alpha + ps;

        // P^T -> Ps (logical [rowq][kv], swizzled image), 4 x h4 writes
#pragma unroll
        for (int cb = 0; cb < 4; ++cb) {
            h4 pk;
            pk[0] = (half_t)p[cb][0]; pk[1] = (half_t)p[cb][1];
            pk[2] = (half_t)p[cb][2]; pk[3] = (half_t)p[cb][3];
            const int s = cb * 2 + (lg >> 1);
            *(h4*)&Ps[rowq * 64 + ((s ^ e7) << 3) + (lg & 1) * 4] = pk;
        }

        // rescale acc rows (q = lg*4+r) by their alpha
        float alphas[4];
#pragma unroll
        for (int r = 0; r < 4; ++r) alphas[r] = __shfl(alpha, lg * 4 + r);
#pragma unroll
        for (int db = 0; db < 4; ++db)
#pragma unroll
            for (int r = 0; r < 4; ++r) acc[db][r] *= alphas[r];

        // O += P V : A=P (row=q, k=kv), B=V^T image (col=d, k=kv)
        const h8 pf0 = *(const h8*)&Ps[rowq * 64 + ((lg ^ e7) << 3)];
        const h8 pf1 = *(const h8*)&Ps[rowq * 64 + (((4 + lg) ^ e7) << 3)];
        __builtin_amdgcn_s_setprio(1);
#pragma unroll
        for (int db = 0; db < 4; ++db) {
            const int rd = db * 16 + lr;
            const h8 vf0 = *(const h8*)&Vs[cur][rd * 64 + ((lg ^ e7) << 3)];
            const h8 vf1 = *(const h8*)&Vs[cur][rd * 64 + (((4 + lg) ^ e7) << 3)];
            acc[db] = __builtin_amdgcn_mfma_f32_16x16x32_f16(pf0, vf0, acc[db], 0, 0, 0);
            acc[db] = __builtin_amdgcn_mfma_f32_16x16x32_f16(pf1, vf1, acc[db], 0, 0, 0);
        }
        __builtin_amdgcn_s_setprio(0);

        __syncthreads();
    }
#undef STAGE

    // epilogue: rows q = lg*4+r need 1/lsum of that q (lives in lane lr=q)
    const float inv = 1.f / lsum;
    float invs[4];
#pragma unroll
    for (int r = 0; r < 4; ++r) invs[r] = __shfl(inv, lg * 4 + r);

    half_t* Ob = O + ((size_t)b * NX + q0 + w * 16) * DIMC + h * HD;
#pragma unroll
    for (int db = 0; db < 4; ++db)
#pragma unroll
        for (int r = 0; r < 4; ++r)
            Ob[(size_t)(lg * 4 + r) * DIMC + db * 16 + lr] =
                (half_t)(acc[db][r] * invs[r]);
}

// ---------------------------------------------------------------------------
extern "C" void kernel_launch(void* const* d_in, const int* in_sizes, int n_in,
                              void* d_out, int out_size, void* d_ws, size_t ws_size,
                              hipStream_t stream)
{
    const float* x     = (const float*)d_in[0];
    const float* c     = (const float*)d_in[1];
    const float* xpe   = (const float*)d_in[2];
    const float* cpe   = (const float*)d_in[3];
    const float* Wq    = (const float*)d_in[4];
    const float* Wkv   = (const float*)d_in[5];
    const float* Wproj = (const float*)d_in[6];
    const float* bproj = (const float*)d_in[7];

    char* wsb = (char*)d_ws;
    half_t* xh  = (half_t*)(wsb);                          // 8 MB
    half_t* ch  = (half_t*)(wsb + ((size_t)8  << 20));     // 16 MB
    half_t* Wqt = (half_t*)(wsb + ((size_t)24 << 20));     // 2 MB
    half_t* Wkt = (half_t*)(wsb + ((size_t)26 << 20));     // 4 MB
    half_t* Wpt = (half_t*)(wsb + ((size_t)30 << 20));     // 2 MB
    half_t* Kw  = (half_t*)(wsb + ((size_t)32 << 20));     // 16 MB (tile image)
    half_t* Vw  = (half_t*)(wsb + ((size_t)48 << 20));     // 16 MB (tile image)
    half_t* Ow  = (half_t*)(wsb + ((size_t)64 << 20));     // 8 MB
    half_t* Qw  = (half_t*)d_out;   // 8 MB of the 16 MB out buffer; attn
                                    // consumes it before hgemm<2> overwrites.

    cvt16<<<2048, 256, 0, stream>>>(x, xh, NB * NX * DIMC);
    cvt16<<<4096, 256, 0, stream>>>(c, ch, NB * NC * DIMC);
    wtrans<<<dim3(16, 16), 256, 0, stream>>>(Wq, Wqt, DIMC);
    wtrans<<<dim3(32, 16), 256, 0, stream>>>(Wkv, Wkt, 2 * DIMC);
    wtrans<<<dim3(16, 16), 256, 0, stream>>>(Wproj, Wpt, DIMC);

    hgemm<0><<<dim3(8, 32), 256, 0, stream>>>(xh, Wqt, xpe, nullptr,
                                              Qw, nullptr, NB * NX, DIMC);
    hgemm<1><<<dim3(16, 64), 256, 0, stream>>>(ch, Wkt, cpe, nullptr,
                                               Kw, Vw, NB * NC, 2 * DIMC);
    attn_mfma<<<1024, 256, 0, stream>>>(Qw, Kw, Vw, Ow);
    hgemm<2><<<dim3(8, 32), 256, 0, stream>>>(Ow, Wpt, nullptr, bproj,
                                              (float*)d_out, nullptr, NB * NX, DIMC);
}

// Round 5
// 194.627 us; speedup vs baseline: 10.8896x; 1.1548x over previous
//
#include <hip/hip_runtime.h>
#include <math.h>

// Shapes (fixed by the problem)
#define DIMC  1024
#define NHEAD 16
#define HD    64
#define NB    4
#define NX    1024
#define NC    2048
#define KD    1024

typedef _Float16 half_t;
typedef __attribute__((ext_vector_type(8))) _Float16 h8;
typedef __attribute__((ext_vector_type(4))) _Float16 h4;
typedef __attribute__((ext_vector_type(4))) float f32x4;

__device__ __forceinline__ void gload_lds16(const half_t* g, half_t* l) {
    __builtin_amdgcn_global_load_lds(
        (__attribute__((address_space(1))) void*)(g),
        (__attribute__((address_space(3))) void*)(l), 16, 0, 0);
}

// ---------------------------------------------------------------------------
// fp32 -> fp16 convert for x and c in one launch (8 elems/thread)
// ---------------------------------------------------------------------------
__global__ __launch_bounds__(256) void cvtboth(
    const float* __restrict__ x, half_t* __restrict__ xh,
    const float* __restrict__ c, half_t* __restrict__ ch)
{
    const int nx = NB * NX * DIMC;
    int i = (blockIdx.x * 256 + threadIdx.x) * 8;
    const float* s;
    half_t* d;
    if (i < nx) { s = x + i; d = xh + i; }
    else        { s = c + (i - nx); d = ch + (i - nx); }
    float4 a = *(const float4*)(s);
    float4 b = *(const float4*)(s + 4);
    h8 o;
    o[0] = (half_t)a.x; o[1] = (half_t)a.y; o[2] = (half_t)a.z; o[3] = (half_t)a.w;
    o[4] = (half_t)b.x; o[5] = (half_t)b.y; o[6] = (half_t)b.z; o[7] = (half_t)b.w;
    *(h8*)d = o;
}

// ---------------------------------------------------------------------------
// cos/sin tables for xpe and cpe (one elem/thread; 768 blocks)
// ---------------------------------------------------------------------------
__global__ __launch_bounds__(256) void mktab(
    const float* __restrict__ xpe, const float* __restrict__ cpe,
    float* __restrict__ xct, float* __restrict__ xst,
    float* __restrict__ cct, float* __restrict__ cst)
{
    const int i = blockIdx.x * 256 + threadIdx.x;
    if (i < NX * HD) {
        const float t = xpe[i];
        xct[i] = cosf(t); xst[i] = sinf(t);
    } else {
        const int j = i - NX * HD;
        const float t = cpe[j];
        cct[j] = cosf(t); cst[j] = sinf(t);
    }
}

// ---------------------------------------------------------------------------
// All three weight transposes in one launch. W (KD x N fp32) -> Wt (N x KD
// fp16), 64x64 tiles.
// ---------------------------------------------------------------------------
__device__ __forceinline__ void wtile(const float* __restrict__ W,
                                      half_t* __restrict__ Wt, int N,
                                      int bx, int by, int t)
{
    __shared__ half_t T[64][72];
    const int k0 = by * 64, n0 = bx * 64;
    const int kr = t >> 2, c0 = (t & 3) << 4;
    const float* src = W + (size_t)(k0 + kr) * N + n0 + c0;
#pragma unroll
    for (int j = 0; j < 16; j += 4) {
        float4 v = *(const float4*)(src + j);
        T[c0 + j + 0][kr] = (half_t)v.x;
        T[c0 + j + 1][kr] = (half_t)v.y;
        T[c0 + j + 2][kr] = (half_t)v.z;
        T[c0 + j + 3][kr] = (half_t)v.w;
    }
    __syncthreads();
    const int nr = t >> 2, kc = (t & 3) << 4;
    half_t* dst = Wt + (size_t)(n0 + nr) * KD + k0 + kc;
    *(int4*)dst       = *(const int4*)&T[nr][kc];
    *(int4*)(dst + 8) = *(const int4*)&T[nr][kc + 8];
}

__global__ __launch_bounds__(256) void wtrans_all(
    const float* __restrict__ Wq,  half_t* __restrict__ Wqt,
    const float* __restrict__ Wkv, half_t* __restrict__ Wkt,
    const float* __restrict__ Wp,  half_t* __restrict__ Wpt)
{
    const int bid = blockIdx.x, t = threadIdx.x;
    if (bid < 256)      wtile(Wq,  Wqt, DIMC,     bid & 15,         bid >> 4,         t);
    else if (bid < 768) wtile(Wkv, Wkt, 2 * DIMC, (bid - 256) & 31, (bid - 256) >> 5, t);
    else                wtile(Wp,  Wpt, DIMC,     (bid - 768) & 15, (bid - 768) >> 4, t);
}

// ---------------------------------------------------------------------------
// fp16 MFMA GEMM: C(Mx BN-tiles) = A(MxK) @ Bt(NxK)^T, fp32 accum.
// BM=128, BK=64, 4 waves. BN=128: 2x2 waves (64x64 each). BN=64: 4x1 waves
// (32x64 each) so the RoPE d^32 partner stays intra-thread (ni^2).
// global_load_lds(16B) with XOR-swizzled source, swizzled ds_read_b128.
// 1-D grid with bijective XCD swizzle (nwg % 8 == 0), bx = lin&15, by=lin>>4.
// MODE 0: RoPE tables * 0.125 -> fp16 out0 (B,H,NX,HD)
// MODE 1: n<1024: RoPE -> fp16 K tile image; n>=1024: fp16 V^T tile image
// MODE 2: + bias -> fp32 out0 row-major (M, DIMC)
// ---------------------------------------------------------------------------
template <int MODE, int BN>
__global__ __launch_bounds__(256) void hgemm(
    const half_t* __restrict__ Ag, const half_t* __restrict__ Bt,
    const float* __restrict__ ct, const float* __restrict__ st,
    const float* __restrict__ bias,
    void* __restrict__ out0, void* __restrict__ out1)
{
    constexpr int MI = (BN == 128) ? 4 : 2;
    constexpr int BLOADS = BN / 32;
    __shared__ half_t As[8192];        // 128 rows x 64 k
    __shared__ half_t Bs[BN * 64];     // BN rows x 64 k

    const int tid = threadIdx.x;
    const int w = tid >> 6, lane = tid & 63;
    const int lr = lane & 15, lg = lane >> 4;
    const int wrOff = (BN == 128) ? (w >> 1) * 64 : w * 32;
    const int wcOff = (BN == 128) ? (w & 1) * 64 : 0;

    // XCD-aware bijective remap of the 1-D grid
    int lin = (int)blockIdx.x;
    lin = (lin & 7) * ((int)gridDim.x >> 3) + (lin >> 3);
    const int m0 = (lin >> 4) * 128, n0 = (lin & 15) * BN;

    f32x4 acc[MI][4];
#pragma unroll
    for (int i = 0; i < MI; ++i)
#pragma unroll
        for (int j = 0; j < 4; ++j) acc[i][j] = f32x4{0.f, 0.f, 0.f, 0.f};

    size_t gA[4], gB[BLOADS];
    int loff[4];
#pragma unroll
    for (int c = 0; c < 4; ++c) {
        const int L = c * 4096 + w * 1024 + lane * 16;
        const int row = L >> 7;
        const int ss = ((L >> 4) & 7) ^ (row & 7);
        gA[c] = (size_t)(m0 + row) * KD + ss * 8;
        if (c < BLOADS) gB[c] = (size_t)(n0 + row) * KD + ss * 8;
        loff[c] = c * 2048 + w * 512;
    }

    for (int k0 = 0; k0 < KD; k0 += 64) {
#pragma unroll
        for (int c = 0; c < 4; ++c) {
            gload_lds16(Ag + gA[c] + k0, As + loff[c]);
            if (c < BLOADS) gload_lds16(Bt + gB[c] + k0, Bs + loff[c]);
        }
        __syncthreads();
#pragma unroll
        for (int kc = 0; kc < 2; ++kc) {
            h8 af[MI], bf[4];
#pragma unroll
            for (int mi = 0; mi < MI; ++mi) {
                const int r = wrOff + mi * 16 + lr;
                af[mi] = *(const h8*)&As[r * 64 + (((kc * 4 + lg) ^ (r & 7)) << 3)];
            }
#pragma unroll
            for (int ni = 0; ni < 4; ++ni) {
                const int r = wcOff + ni * 16 + lr;
                bf[ni] = *(const h8*)&Bs[r * 64 + (((kc * 4 + lg) ^ (r & 7)) << 3)];
            }
#pragma unroll
            for (int mi = 0; mi < MI; ++mi)
#pragma unroll
                for (int ni = 0; ni < 4; ++ni)
                    acc[mi][ni] = __builtin_amdgcn_mfma_f32_16x16x32_f16(
                        af[mi], bf[ni], acc[mi][ni], 0, 0, 0);
        }
        __syncthreads();
    }

    // C/D layout: row = base + lg*4 + r, col = base + lr  (HW-verified)
    if (MODE == 2) {
        float* o = (float*)out0;
#pragma unroll
        for (int ni = 0; ni < 4; ++ni) {
            const int col = n0 + ni * 16 + lr;
            const float bv = bias[col];
#pragma unroll
            for (int mi = 0; mi < MI; ++mi)
#pragma unroll
                for (int r = 0; r < 4; ++r) {
                    const int row = m0 + wrOff + mi * 16 + lg * 4 + r;
                    o[(size_t)row * DIMC + col] = acc[mi][ni][r] + bv;
                }
        }
        return;
    }

    if (MODE == 0) {
        half_t* Qw = (half_t*)out0;
        const int h = n0 >> 6;
#pragma unroll
        for (int mi = 0; mi < MI; ++mi)
#pragma unroll
            for (int r = 0; r < 4; ++r) {
                const int row = m0 + wrOff + mi * 16 + lg * 4 + r;
                const int bb = row >> 10, nn = row & (NX - 1);
                const float* cr = ct + nn * HD;
                const float* sr = st + nn * HD;
                half_t* op = Qw + (((size_t)(bb * NHEAD + h)) * NX + nn) * HD;
#pragma unroll
                for (int ni = 0; ni < 4; ++ni) {
                    const int d = ni * 16 + lr;
                    const float val = acc[mi][ni][r];
                    const float pv  = acc[mi][ni ^ 2][r];   // d ^ 32 partner
                    op[d] = (half_t)((val * cr[d] + (ni < 2 ? -pv : pv) * sr[d]) * 0.125f);
                }
            }
    } else {  // MODE 1: K/V in swizzled LDS-tile-image global layouts
        const bool isK = (n0 < DIMC);
        const int h = ((n0 & (DIMC - 1)) >> 6) + (w & 1);
        half_t* Kw = (half_t*)out0;
        half_t* Vw = (half_t*)out1;
#pragma unroll
        for (int mi = 0; mi < MI; ++mi)
#pragma unroll
            for (int r = 0; r < 4; ++r) {
                const int row = m0 + wrOff + mi * 16 + lg * 4 + r;
                const int bb = row >> 11, nn = row & (NC - 1);
                const int tt = nn >> 6, rr = nn & 63;
                const size_t tbase = ((size_t)(bb * NHEAD + h) * 32 + tt) * 4096;
                const float* cr = ct + nn * HD;
                const float* sr = st + nn * HD;
#pragma unroll
                for (int ni = 0; ni < 4; ++ni) {
                    const int d = ni * 16 + lr;
                    const float val = acc[mi][ni][r];
                    if (isK) {
                        const float pv = acc[mi][ni ^ 2][r];
                        Kw[tbase + rr * 64 + ((((d >> 3) ^ (rr & 7)) << 3) | (d & 7))] =
                            (half_t)(val * cr[d] + (ni < 2 ? -pv : pv) * sr[d]);
                    } else {
                        Vw[tbase + d * 64 + ((((rr >> 3) ^ (d & 7)) << 3) | (rr & 7))] =
                            (half_t)val;
                    }
                }
            }
    }
}

// ---------------------------------------------------------------------------
// Swapped-operand MFMA flash attention (fp16). 4 waves, 64 q-rows (16/wave),
// kv-tiles of 64, double-buffered K/V staged by global_load_lds from the
// pre-swizzled global tile images. S^T = K Q^T so softmax is lane-local.
// T13 defer-max: skip O-rescale while the running max grows by <= 8.
// ---------------------------------------------------------------------------
__global__ __launch_bounds__(256) void attn_mfma(
    const half_t* __restrict__ Q, const half_t* __restrict__ Kg,
    const half_t* __restrict__ Vg, half_t* __restrict__ O)
{
    __shared__ half_t Ks[2][4096];   // swizzled K tile image [kv][d]
    __shared__ half_t Vs[2][4096];   // swizzled V^T tile image [d][kv]
    __shared__ half_t Ps[4096];      // swizzled P [q][kv], wave-private rows

    const int tid = threadIdx.x;
    const int w = tid >> 6, lane = tid & 63;
    const int lr = lane & 15, lg = lane >> 4;
    const int e7 = lr & 7;

    // XCD swizzle: 1024 blocks -> 8 chunks of 128; 16 q-blocks/bh stay on-XCD
    const int sid = (blockIdx.x & 7) * 128 + (blockIdx.x >> 3);
    const int bh = sid >> 4;
    const int q0 = (sid & 15) * 64;
    const int b = bh >> 4, h = bh & 15;

    // Q fragments (q = q0 + w*16 + lr), 0.125 scale prefolded by hgemm<0>
    const half_t* qbase = Q + ((size_t)bh * NX + q0 + w * 16 + lr) * HD + lg * 8;
    const h8 qf0 = *(const h8*)(qbase);
    const h8 qf1 = *(const h8*)(qbase + 32);

    f32x4 acc[4];
#pragma unroll
    for (int i = 0; i < 4; ++i) acc[i] = f32x4{0.f, 0.f, 0.f, 0.f};
    float mrun = -INFINITY, lsum = 0.f;

    const half_t* Kt = Kg + (size_t)bh * 32 * 4096;
    const half_t* Vt = Vg + (size_t)bh * 32 * 4096;
    const int so = w * 512 + lane * 8;   // per-lane half offset within tile

#define STAGE(bi, t) do {                                           \
        const half_t* kg_ = Kt + (size_t)(t) * 4096;                \
        const half_t* vg_ = Vt + (size_t)(t) * 4096;                \
        gload_lds16(kg_ + so,        &Ks[bi][w * 512]);             \
        gload_lds16(kg_ + 2048 + so, &Ks[bi][2048 + w * 512]);      \
        gload_lds16(vg_ + so,        &Vs[bi][w * 512]);             \
        gload_lds16(vg_ + 2048 + so, &Vs[bi][2048 + w * 512]);      \
    } while (0)

    STAGE(0, 0);
    __syncthreads();

    const int rowq = w * 16 + lr;        // this lane's q row (local)

    for (int t = 0; t < NC / 64; ++t) {
        const int cur = t & 1;
        if (t + 1 < NC / 64) STAGE(cur ^ 1, t + 1);

        // S^T = K Q^T : A=K rows (kv), B=Q (col=q). Lane: q=lr fixed,
        // scores at kv = cb*16 + lg*4 + r.
        f32x4 sc[4];
        __builtin_amdgcn_s_setprio(1);
#pragma unroll
        for (int cb = 0; cb < 4; ++cb) {
            const int r = cb * 16 + lr;
            const h8 kf0 = *(const h8*)&Ks[cur][r * 64 + ((lg ^ e7) << 3)];
            const h8 kf1 = *(const h8*)&Ks[cur][r * 64 + (((4 + lg) ^ e7) << 3)];
            f32x4 a = {0.f, 0.f, 0.f, 0.f};
            a = __builtin_amdgcn_mfma_f32_16x16x32_f16(kf0, qf0, a, 0, 0, 0);
            a = __builtin_amdgcn_mfma_f32_16x16x32_f16(kf1, qf1, a, 0, 0, 0);
            sc[cb] = a;
        }
        __builtin_amdgcn_s_setprio(0);

        // lane-local softmax over 16 scores + 2 cross-lg shuffles
        float m16 = sc[0][0];
#pragma unroll
        for (int cb = 0; cb < 4; ++cb)
#pragma unroll
            for (int r = 0; r < 4; ++r) m16 = fmaxf(m16, sc[cb][r]);
        m16 = fmaxf(m16, __shfl_xor(m16, 16));
        m16 = fmaxf(m16, __shfl_xor(m16, 32));
        // defer-max: keep old max while growth <= 8 (P bounded by e^8)
        const float mnew = (m16 - mrun <= 8.f) ? mrun : m16;
        const float alpha = __expf(mrun - mnew);   // 1.0 when kept
        mrun = mnew;

        float p[4][4];
        float ps = 0.f;
#pragma unroll
        for (int cb = 0; cb < 4; ++cb)
#pragma unroll
            for (int r = 0; r < 4; ++r) {
                p[cb][r] = __expf(sc[cb][r] - mnew);
                ps += p[cb][r];
            }
        ps += __shfl_xor(ps, 16);
        ps += __shfl_xor(ps, 32);
        lsum = lsum * alpha + ps;

        // P^T -> Ps (logical [rowq][kv], swizzled image), 4 x h4 writes
#pragma unroll
        for (int cb = 0; cb < 4; ++cb) {
            h4 pk;
            pk[0] = (half_t)p[cb][0]; pk[1] = (half_t)p[cb][1];
            pk[2] = (half_t)p[cb][2]; pk[3] = (half_t)p[cb][3];
            const int s = cb * 2 + (lg >> 1);
            *(h4*)&Ps[rowq * 64 + ((s ^ e7) << 3) + (lg & 1) * 4] = pk;
        }

        // rescale acc rows (q = lg*4+r) by their alpha, only if any changed
        if (__any(alpha != 1.f)) {
            float alphas[4];
#pragma unroll
            for (int r = 0; r < 4; ++r) alphas[r] = __shfl(alpha, lg * 4 + r);
#pragma unroll
            for (int db = 0; db < 4; ++db)
#pragma unroll
                for (int r = 0; r < 4; ++r) acc[db][r] *= alphas[r];
        }

        // O += P V : A=P (row=q, k=kv), B=V^T image (col=d, k=kv)
        const h8 pf0 = *(const h8*)&Ps[rowq * 64 + ((lg ^ e7) << 3)];
        const h8 pf1 = *(const h8*)&Ps[rowq * 64 + (((4 + lg) ^ e7) << 3)];
        __builtin_amdgcn_s_setprio(1);
#pragma unroll
        for (int db = 0; db < 4; ++db) {
            const int rd = db * 16 + lr;
            const h8 vf0 = *(const h8*)&Vs[cur][rd * 64 + ((lg ^ e7) << 3)];
            const h8 vf1 = *(const h8*)&Vs[cur][rd * 64 + (((4 + lg) ^ e7) << 3)];
            acc[db] = __builtin_amdgcn_mfma_f32_16x16x32_f16(pf0, vf0, acc[db], 0, 0, 0);
            acc[db] = __builtin_amdgcn_mfma_f32_16x16x32_f16(pf1, vf1, acc[db], 0, 0, 0);
        }
        __builtin_amdgcn_s_setprio(0);

        __syncthreads();
    }
#undef STAGE

    // epilogue: rows q = lg*4+r need 1/lsum of that q (lives in lane lr=q)
    const float inv = 1.f / lsum;
    float invs[4];
#pragma unroll
    for (int r = 0; r < 4; ++r) invs[r] = __shfl(inv, lg * 4 + r);

    half_t* Ob = O + ((size_t)b * NX + q0 + w * 16) * DIMC + h * HD;
#pragma unroll
    for (int db = 0; db < 4; ++db)
#pragma unroll
        for (int r = 0; r < 4; ++r)
            Ob[(size_t)(lg * 4 + r) * DIMC + db * 16 + lr] =
                (half_t)(acc[db][r] * invs[r]);
}

// ---------------------------------------------------------------------------
extern "C" void kernel_launch(void* const* d_in, const int* in_sizes, int n_in,
                              void* d_out, int out_size, void* d_ws, size_t ws_size,
                              hipStream_t stream)
{
    const float* x     = (const float*)d_in[0];
    const float* c     = (const float*)d_in[1];
    const float* xpe   = (const float*)d_in[2];
    const float* cpe   = (const float*)d_in[3];
    const float* Wq    = (const float*)d_in[4];
    const float* Wkv   = (const float*)d_in[5];
    const float* Wproj = (const float*)d_in[6];
    const float* bproj = (const float*)d_in[7];

    char* wsb = (char*)d_ws;
    half_t* xh  = (half_t*)(wsb);                          // 8 MB
    half_t* ch  = (half_t*)(wsb + ((size_t)8  << 20));     // 16 MB
    half_t* Wqt = (half_t*)(wsb + ((size_t)24 << 20));     // 2 MB
    half_t* Wkt = (half_t*)(wsb + ((size_t)26 << 20));     // 4 MB
    half_t* Wpt = (half_t*)(wsb + ((size_t)30 << 20));     // 2 MB
    half_t* Kw  = (half_t*)(wsb + ((size_t)32 << 20));     // 16 MB (tile image)
    half_t* Vw  = (half_t*)(wsb + ((size_t)48 << 20));     // 16 MB (tile image)
    half_t* Ow  = (half_t*)(wsb + ((size_t)64 << 20));     // 8 MB
    float*  xct = (float*)(wsb + ((size_t)72 << 20));      // 256 KB
    float*  xst = (float*)(wsb + ((size_t)72 << 20) + (256u << 10));
    float*  cct = (float*)(wsb + ((size_t)72 << 20) + (512u << 10));
    float*  cst = (float*)(wsb + ((size_t)72 << 20) + (1024u << 10));
    half_t* Qw  = (half_t*)d_out;   // 8 MB of the 16 MB out buffer; attn
                                    // consumes it before hgemm<2> overwrites.

    cvtboth<<<6144, 256, 0, stream>>>(x, xh, c, ch);
    mktab<<<768, 256, 0, stream>>>(xpe, cpe, xct, xst, cct, cst);
    wtrans_all<<<1024, 256, 0, stream>>>(Wq, Wqt, Wkv, Wkt, Wproj, Wpt);

    hgemm<0, 64><<<512, 256, 0, stream>>>(xh, Wqt, xct, xst, nullptr,
                                          Qw, nullptr);
    hgemm<1, 128><<<1024, 256, 0, stream>>>(ch, Wkt, cct, cst, nullptr,
                                            Kw, Vw);
    attn_mfma<<<1024, 256, 0, stream>>>(Qw, Kw, Vw, Ow);
    hgemm<2, 64><<<512, 256, 0, stream>>>(Ow, Wpt, nullptr, nullptr, bproj,
                                          (float*)d_out, nullptr);
}